// Round 10
// baseline (37.711 us; speedup 1.0000x reference)
//
#include <hip/hip_runtime.h>

#define NB 8
#define NC 4
#define NH 256
#define NW 256
#define HW (NH * NW)      // 65536
#define CHW (NC * HW)     // 262144
#define INFV 1e10f
#define TH 4                              // output rows per block
#define MAIN_BLOCKS (NB * (NH / TH))      // 512
#define WR (TH + 8)                       // window rows held in registers (12)

// ---------------------------------------------------------------------------
// K1: EDT pass 1 along W — ballot version (proven R6/R8 interior).
// One block (256 thr) per (b,h). Output layout CHANGED to channel-interleaved
// Dp[b][h][w][c] u16: one coalesced uint2 store per thread (was 4 strided).
// 65535 = class absent from row (reference: 1e10); else exact d^2 <= 65025.
// ---------------------------------------------------------------------------
__global__ __launch_bounds__(256) void k_edt_w(const int* __restrict__ tgt,
                                               unsigned short* __restrict__ Dp) {
    int bh = blockIdx.x;            // b*NH + h
    int i  = threadIdx.x;
    int wv = i >> 6;                // wave id (0..3)
    int ln = i & 63;

    int tv = tgt[(size_t)bh * NW + i];

    __shared__ unsigned long long mk[NC][4];
    #pragma unroll
    for (int c = 0; c < NC; ++c) {
        unsigned long long m = __ballot(tv == c);
        if (ln == 0) mk[c][wv] = m;
    }
    __syncthreads();

    unsigned long long le = (ln == 63) ? ~0ull : ((1ull << (ln + 1)) - 1ull);
    unsigned long long ge = ~0ull << ln;

    unsigned res[NC];
    #pragma unroll
    for (int c = 0; c < NC; ++c) {
        int jl = -1000;
        #pragma unroll
        for (int k = 0; k < 4; ++k) {
            unsigned long long x = mk[c][k];
            x = (k > wv) ? 0ull : ((k == wv) ? (x & le) : x);
            if (x) jl = k * 64 + 63 - __clzll((long long)x);
        }
        int jr = 1000;
        #pragma unroll
        for (int k = 3; k >= 0; --k) {
            unsigned long long x = mk[c][k];
            x = (k < wv) ? 0ull : ((k == wv) ? (x & ge) : x);
            if (x) jr = k * 64 + __ffsll((unsigned long long)x) - 1;
        }
        int dd = min(i - jl, jr - i);
        res[c] = (dd > 255) ? 65535u : (unsigned)(dd * dd);
    }

    uint2 pk;
    pk.x = res[0] | (res[1] << 16);
    pk.y = res[2] | (res[3] << 16);
    *(uint2*)(Dp + ((size_t)bh * NW + i) * NC) = pk;   // 8B/thread, coalesced
}

// ---------------------------------------------------------------------------
// softmax of the 4 channel logits at pixel offset hw of batch-base pred_b.
// ---------------------------------------------------------------------------
__device__ __forceinline__ void softmax4(const float* __restrict__ pred_b,
                                         int hw, float o[NC]) {
    float x0 = pred_b[hw];
    float x1 = pred_b[hw + HW];
    float x2 = pred_b[hw + 2 * HW];
    float x3 = pred_b[hw + 3 * HW];
    float m  = fmaxf(fmaxf(x0, x1), fmaxf(x2, x3));
    float e0 = __expf(x0 - m);
    float e1 = __expf(x1 - m);
    float e2 = __expf(x2 - m);
    float e3 = __expf(x3 - m);
    float inv = 1.0f / (e0 + e1 + e2 + e3);
    o[0] = e0 * inv; o[1] = e1 * inv; o[2] = e2 * inv; o[3] = e3 * inv;
}

// ---------------------------------------------------------------------------
// K2: fused kernel (R8 interior + interleaved D + fused final reduction).
// Block = 256 threads (w) x TH=4 output rows.
//  - D window rows h0-4..h0+7: 12 coalesced uint2 loads/thread (was 48 scalar)
//  - softmax p staged once in LDS for the 6x258 halo; stencil reads LDS
//  - per-px window min (exact cutoff 25) + rare exact fallback scan
//  - block partial -> global; LAST block reduces all partials -> out
// ---------------------------------------------------------------------------
__global__ __launch_bounds__(256) void k_main(const float* __restrict__ pred,
                                              const unsigned short* __restrict__ Dp,
                                              float2* __restrict__ partial,
                                              unsigned* __restrict__ cnt,
                                              float* __restrict__ out) {
    int blk  = blockIdx.x;          // b*64 + tile
    int b    = blk >> 6;
    int tile = blk & 63;
    int h0   = tile * TH;
    int w    = threadIdx.x;

    const float* pred_b = pred + (size_t)b * CHW;

    // ---- D register window: 12 guarded uint2 loads (fully unrolled) ----
    float win[WR][NC];
    #pragma unroll
    for (int k = 0; k < WR; ++k) {
        int j   = h0 - 4 + k;
        bool ok = (unsigned)j < (unsigned)NH;
        uint2 v;
        if (ok) v = *(const uint2*)(Dp + (((size_t)b * NH + j) * NW + w) * NC);
        else    { v.x = 0xFFFFFFFFu; v.y = 0xFFFFFFFFu; }
        unsigned a0 = v.x & 0xFFFFu, a1 = v.x >> 16;
        unsigned a2 = v.y & 0xFFFFu, a3 = v.y >> 16;
        win[k][0] = (a0 > 65025u) ? INFV : (float)a0;
        win[k][1] = (a1 > 65025u) ? INFV : (float)a1;
        win[k][2] = (a2 > 65025u) ? INFV : (float)a2;
        win[k][3] = (a3 > 65025u) ? INFV : (float)a3;
    }

    // ---- stage softmax p for the halo (rows h0-1..h0+4, cols -1..256) ----
    __shared__ float ps[NC][TH + 2][NW + 2];
    for (int pos = threadIdx.x; pos < (TH + 2) * (NW + 2); pos += 256) {
        int row = pos / (NW + 2);          // 0..5
        int col = pos - row * (NW + 2);    // 0..257
        int gy  = h0 - 1 + row;
        int gx  = col - 1;
        float o[NC] = {0.0f, 0.0f, 0.0f, 0.0f};   // zero pad outside image
        if ((unsigned)gy < (unsigned)NH && (unsigned)gx < (unsigned)NW)
            softmax4(pred_b, (gy << 8) + gx, o);
        ps[0][row][col] = o[0];
        ps[1][row][col] = o[1];
        ps[2][row][col] = o[2];
        ps[3][row][col] = o[3];
    }
    __syncthreads();

    float num = 0.0f, den = 0.0f;
    #pragma unroll
    for (int r = 0; r < TH; ++r) {
        int h = h0 + r;
        #pragma unroll
        for (int c = 0; c < NC; ++c) {
            float lap = fabsf(ps[c][r][w + 1] + ps[c][r + 2][w + 1]
                            + ps[c][r + 1][w] + ps[c][r + 1][w + 2]
                            - 4.0f * ps[c][r + 1][w + 1]);

            // window min from registers (all adds exact: ints <= 65041)
            float best = win[r + 4][c];
            #pragma unroll
            for (int dr = 1; dr <= 4; ++dr) {
                float rr = (float)(dr * dr);
                best = fminf(best, rr + win[r + 4 - dr][c]);
                best = fminf(best, rr + win[r + 4 + dr][c]);
            }

            // exact fallback for best > 25 (rare; also the empty/absent-
            // channel path, which masks to 0 like the reference).
            if (best > 25.0f) {
                const unsigned short* f = Dp + (size_t)b * NH * NW * NC
                                        + (size_t)w * NC + c;
                for (int r2 = 5; r2 < NH; ++r2) {
                    float rr = (float)(r2 * r2);   // exact int <= 65025
                    if (rr >= best) break;
                    int hu = h - r2, hd = h + r2;
                    if (hu >= 0) {
                        unsigned short u = f[(size_t)hu * NW * NC];
                        if (u <= 65025) best = fminf(best, rr + (float)u);
                    }
                    if (hd < NH) {
                        unsigned short u = f[(size_t)hd * NW * NC];
                        if (u <= 65025) best = fminf(best, rr + (float)u);
                    }
                }
            }

            float dv = (best > 1e8f) ? 0.0f : sqrtf(best); // empty-ch mask
            num += lap * dv;
            den += lap;
        }
    }

    #pragma unroll
    for (int off = 32; off > 0; off >>= 1) {
        num += __shfl_down(num, off);
        den += __shfl_down(den, off);
    }
    __shared__ float sn[4], sd[4];
    int lane = threadIdx.x & 63;
    int wvi  = threadIdx.x >> 6;
    if (lane == 0) { sn[wvi] = num; sd[wvi] = den; }
    __syncthreads();

    __shared__ bool amLast;
    if (threadIdx.x == 0) {
        partial[blockIdx.x] = make_float2(sn[0] + sn[1] + sn[2] + sn[3],
                                          sd[0] + sd[1] + sd[2] + sd[3]);
        __threadfence();                       // partial visible device-wide
        unsigned old = atomicAdd(cnt, 1u);     // device-scope
        amLast = (old == MAIN_BLOCKS - 1);
    }
    __syncthreads();

    if (amLast) {
        __threadfence();                       // acquire: see all partials
        double n = 0.0, d = 0.0;
        for (int i = threadIdx.x; i < MAIN_BLOCKS; i += 256) {
            float2 v = partial[i];
            n += (double)v.x;
            d += (double)v.y;
        }
        #pragma unroll
        for (int off = 32; off > 0; off >>= 1) {
            n += __shfl_down(n, off);
            d += __shfl_down(d, off);
        }
        __shared__ double snd[4], sdd[4];
        if (lane == 0) { snd[wvi] = n; sdd[wvi] = d; }
        __syncthreads();
        if (threadIdx.x == 0) {
            double nn = snd[0] + snd[1] + snd[2] + snd[3];
            double dd = sdd[0] + sdd[1] + sdd[2] + sdd[3];
            out[0] = (float)(nn / dd);
        }
    }
}

extern "C" void kernel_launch(void* const* d_in, const int* in_sizes, int n_in,
                              void* d_out, int out_size, void* d_ws, size_t ws_size,
                              hipStream_t stream) {
    const float* pred = (const float*)d_in[0];
    const int*   tgt  = (const int*)d_in[1];
    float*       out  = (float*)d_out;

    unsigned short* Dp      = (unsigned short*)d_ws;                 // 4 MB
    float2*         partial = (float2*)((char*)d_ws + (size_t)NB * CHW * 2);
    unsigned*       cnt     = (unsigned*)(partial + MAIN_BLOCKS);

    hipMemsetAsync(cnt, 0, sizeof(unsigned), stream);
    k_edt_w<<<NB * NH,     256, 0, stream>>>(tgt, Dp);
    k_main <<<MAIN_BLOCKS, 256, 0, stream>>>(pred, Dp, partial, cnt, out);
}

// Round 11
// 24.559 us; speedup vs baseline: 1.5355x; 1.5355x over previous
//
#include <hip/hip_runtime.h>

#define NB 8
#define NC 4
#define NH 256
#define NW 256
#define HW (NH * NW)      // 65536
#define CHW (NC * HW)     // 262144
#define INFV 1e10f
#define TH 4                              // output rows per block
#define MAIN_BLOCKS (NB * (NH / TH))      // 512
#define WR (TH + 8)                       // window rows held in registers (12)

// ---------------------------------------------------------------------------
// K1: EDT pass 1 along W — ballot version (proven R6/R8 interior).
// One block (256 thr) per (b,h). Output channel-interleaved Dp[b][h][w][c]
// u16: one coalesced uint2 store per thread. 65535 = class absent from row
// (reference: 1e10); else exact d^2 <= 65025.
// ---------------------------------------------------------------------------
__global__ __launch_bounds__(256) void k_edt_w(const int* __restrict__ tgt,
                                               unsigned short* __restrict__ Dp) {
    int bh = blockIdx.x;            // b*NH + h
    int i  = threadIdx.x;
    int wv = i >> 6;                // wave id (0..3)
    int ln = i & 63;

    int tv = tgt[(size_t)bh * NW + i];

    __shared__ unsigned long long mk[NC][4];
    #pragma unroll
    for (int c = 0; c < NC; ++c) {
        unsigned long long m = __ballot(tv == c);
        if (ln == 0) mk[c][wv] = m;
    }
    __syncthreads();

    unsigned long long le = (ln == 63) ? ~0ull : ((1ull << (ln + 1)) - 1ull);
    unsigned long long ge = ~0ull << ln;

    unsigned res[NC];
    #pragma unroll
    for (int c = 0; c < NC; ++c) {
        int jl = -1000;
        #pragma unroll
        for (int k = 0; k < 4; ++k) {
            unsigned long long x = mk[c][k];
            x = (k > wv) ? 0ull : ((k == wv) ? (x & le) : x);
            if (x) jl = k * 64 + 63 - __clzll((long long)x);
        }
        int jr = 1000;
        #pragma unroll
        for (int k = 3; k >= 0; --k) {
            unsigned long long x = mk[c][k];
            x = (k < wv) ? 0ull : ((k == wv) ? (x & ge) : x);
            if (x) jr = k * 64 + __ffsll((unsigned long long)x) - 1;
        }
        int dd = min(i - jl, jr - i);
        res[c] = (dd > 255) ? 65535u : (unsigned)(dd * dd);
    }

    uint2 pk;
    pk.x = res[0] | (res[1] << 16);
    pk.y = res[2] | (res[3] << 16);
    *(uint2*)(Dp + ((size_t)bh * NW + i) * NC) = pk;   // 8B/thread, coalesced
}

// ---------------------------------------------------------------------------
// softmax of the 4 channel logits at pixel offset hw of batch-base pred_b.
// ---------------------------------------------------------------------------
__device__ __forceinline__ void softmax4(const float* __restrict__ pred_b,
                                         int hw, float o[NC]) {
    float x0 = pred_b[hw];
    float x1 = pred_b[hw + HW];
    float x2 = pred_b[hw + 2 * HW];
    float x3 = pred_b[hw + 3 * HW];
    float m  = fmaxf(fmaxf(x0, x1), fmaxf(x2, x3));
    float e0 = __expf(x0 - m);
    float e1 = __expf(x1 - m);
    float e2 = __expf(x2 - m);
    float e3 = __expf(x3 - m);
    float inv = 1.0f / (e0 + e1 + e2 + e3);
    o[0] = e0 * inv; o[1] = e1 * inv; o[2] = e2 * inv; o[3] = e3 * inv;
}

// ---------------------------------------------------------------------------
// K2: fused kernel (R8 structure, interleaved-D window loads).
// Block = 256 threads (w) x TH=4 output rows.
//  - D window rows h0-4..h0+7: 12 coalesced uint2 loads/thread (was 48 scalar)
//  - softmax p staged once in LDS for the 6x258 halo; stencil reads LDS
//  - per-px window min (exact cutoff 25) + rare exact fallback scan
//  - block reduction -> partial[block]
// ---------------------------------------------------------------------------
__global__ __launch_bounds__(256) void k_main(const float* __restrict__ pred,
                                              const unsigned short* __restrict__ Dp,
                                              float2* __restrict__ partial) {
    int blk  = blockIdx.x;          // b*64 + tile
    int b    = blk >> 6;
    int tile = blk & 63;
    int h0   = tile * TH;
    int w    = threadIdx.x;

    const float* pred_b = pred + (size_t)b * CHW;

    // ---- D register window: 12 guarded uint2 loads (fully unrolled) ----
    float win[WR][NC];
    #pragma unroll
    for (int k = 0; k < WR; ++k) {
        int j   = h0 - 4 + k;
        bool ok = (unsigned)j < (unsigned)NH;
        uint2 v;
        if (ok) v = *(const uint2*)(Dp + (((size_t)b * NH + j) * NW + w) * NC);
        else    { v.x = 0xFFFFFFFFu; v.y = 0xFFFFFFFFu; }
        unsigned a0 = v.x & 0xFFFFu, a1 = v.x >> 16;
        unsigned a2 = v.y & 0xFFFFu, a3 = v.y >> 16;
        win[k][0] = (a0 > 65025u) ? INFV : (float)a0;
        win[k][1] = (a1 > 65025u) ? INFV : (float)a1;
        win[k][2] = (a2 > 65025u) ? INFV : (float)a2;
        win[k][3] = (a3 > 65025u) ? INFV : (float)a3;
    }

    // ---- stage softmax p for the halo (rows h0-1..h0+4, cols -1..256) ----
    __shared__ float ps[NC][TH + 2][NW + 2];
    for (int pos = threadIdx.x; pos < (TH + 2) * (NW + 2); pos += 256) {
        int row = pos / (NW + 2);          // 0..5
        int col = pos - row * (NW + 2);    // 0..257
        int gy  = h0 - 1 + row;
        int gx  = col - 1;
        float o[NC] = {0.0f, 0.0f, 0.0f, 0.0f};   // zero pad outside image
        if ((unsigned)gy < (unsigned)NH && (unsigned)gx < (unsigned)NW)
            softmax4(pred_b, (gy << 8) + gx, o);
        ps[0][row][col] = o[0];
        ps[1][row][col] = o[1];
        ps[2][row][col] = o[2];
        ps[3][row][col] = o[3];
    }
    __syncthreads();

    float num = 0.0f, den = 0.0f;
    #pragma unroll
    for (int r = 0; r < TH; ++r) {
        int h = h0 + r;
        #pragma unroll
        for (int c = 0; c < NC; ++c) {
            float lap = fabsf(ps[c][r][w + 1] + ps[c][r + 2][w + 1]
                            + ps[c][r + 1][w] + ps[c][r + 1][w + 2]
                            - 4.0f * ps[c][r + 1][w + 1]);

            // window min from registers (all adds exact: ints <= 65041)
            float best = win[r + 4][c];
            #pragma unroll
            for (int dr = 1; dr <= 4; ++dr) {
                float rr = (float)(dr * dr);
                best = fminf(best, rr + win[r + 4 - dr][c]);
                best = fminf(best, rr + win[r + 4 + dr][c]);
            }

            // exact fallback for best > 25 (rare; also the empty/absent-
            // channel path, which masks to 0 like the reference).
            if (best > 25.0f) {
                const unsigned short* f = Dp + (size_t)b * NH * NW * NC
                                        + (size_t)w * NC + c;
                for (int r2 = 5; r2 < NH; ++r2) {
                    float rr = (float)(r2 * r2);   // exact int <= 65025
                    if (rr >= best) break;
                    int hu = h - r2, hd = h + r2;
                    if (hu >= 0) {
                        unsigned short u = f[(size_t)hu * NW * NC];
                        if (u <= 65025) best = fminf(best, rr + (float)u);
                    }
                    if (hd < NH) {
                        unsigned short u = f[(size_t)hd * NW * NC];
                        if (u <= 65025) best = fminf(best, rr + (float)u);
                    }
                }
            }

            float dv = (best > 1e8f) ? 0.0f : sqrtf(best); // empty-ch mask
            num += lap * dv;
            den += lap;
        }
    }

    #pragma unroll
    for (int off = 32; off > 0; off >>= 1) {
        num += __shfl_down(num, off);
        den += __shfl_down(den, off);
    }
    __shared__ float sn[4], sd[4];
    int lane = threadIdx.x & 63;
    int wvi  = threadIdx.x >> 6;
    if (lane == 0) { sn[wvi] = num; sd[wvi] = den; }
    __syncthreads();
    if (threadIdx.x == 0) {
        partial[blockIdx.x] = make_float2(sn[0] + sn[1] + sn[2] + sn[3],
                                          sd[0] + sd[1] + sd[2] + sd[3]);
    }
}

// ---------------------------------------------------------------------------
// K3: final reduction of partials + divide. One block.
// ---------------------------------------------------------------------------
__global__ __launch_bounds__(256) void k_final(const float2* __restrict__ partial,
                                               float* __restrict__ out) {
    double n = 0.0, d = 0.0;
    for (int i = threadIdx.x; i < MAIN_BLOCKS; i += 256) {
        float2 v = partial[i];
        n += (double)v.x;
        d += (double)v.y;
    }
    #pragma unroll
    for (int off = 32; off > 0; off >>= 1) {
        n += __shfl_down(n, off);
        d += __shfl_down(d, off);
    }
    __shared__ double snd[4], sdd[4];
    int lane = threadIdx.x & 63;
    int wv   = threadIdx.x >> 6;
    if (lane == 0) { snd[wv] = n; sdd[wv] = d; }
    __syncthreads();
    if (threadIdx.x == 0) {
        double nn = snd[0] + snd[1] + snd[2] + snd[3];
        double dd = sdd[0] + sdd[1] + sdd[2] + sdd[3];
        out[0] = (float)(nn / dd);
    }
}

extern "C" void kernel_launch(void* const* d_in, const int* in_sizes, int n_in,
                              void* d_out, int out_size, void* d_ws, size_t ws_size,
                              hipStream_t stream) {
    const float* pred = (const float*)d_in[0];
    const int*   tgt  = (const int*)d_in[1];
    float*       out  = (float*)d_out;

    unsigned short* Dp      = (unsigned short*)d_ws;                 // 4 MB
    float2*         partial = (float2*)((char*)d_ws + (size_t)NB * CHW * 2);

    k_edt_w<<<NB * NH,     256, 0, stream>>>(tgt, Dp);
    k_main <<<MAIN_BLOCKS, 256, 0, stream>>>(pred, Dp, partial);
    k_final<<<1,           256, 0, stream>>>(partial, out);
}